// Round 8
// baseline (157.066 us; speedup 1.0000x reference)
//
#include <hip/hip_runtime.h>
#include <hip/hip_bf16.h>

// Stratified max pooling: out[b,c] = max over j with labels[j]==c of values[b,j]
// values: [B, N] fp32, labels: [N] int32, out: [B, C] fp32.
//
// Round 8: single-variable test vs round 7 — REGULAR loads instead of
// nontemporal. Round 7's contiguous-span streaming broke the 2.2 TB/s
// invariant (kernel ~15 us), but nt-loads evicted `values` from L3, slowing
// the harness's restore copy (61.5 us, FETCH 50 MB). Regular loads should
// keep the streaming win AND keep values L3-resident (faster kernel reads +
// faster restore). Everything else is byte-identical to round 7.

#define TPBS 256
#define SMAX 16                  // column splits per row
#define ENC_NEG_INF 0x007FFFFFu  // enc(-inf)

typedef float f4 __attribute__((ext_vector_type(4)));

__device__ __forceinline__ unsigned enc32(unsigned u) {
    // monotone float->uint: neg -> ~u, pos -> u|0x80000000  (branchless)
    return u ^ ((unsigned)(((int)u) >> 31) | 0x80000000u);
}
__device__ __forceinline__ float dec32(unsigned u) {
    unsigned b = u ^ (~(unsigned)(((int)u) >> 31) | 0x80000000u);
    return __uint_as_float(b);
}

// pack labels to u8 (valid: C <= 128 on main path)
__global__ __launch_bounds__(TPBS) void strat_lab8(
    const int* __restrict__ labels, unsigned char* __restrict__ l8, int N) {
    int i = blockIdx.x * TPBS + threadIdx.x;
    if (i < N) l8[i] = (unsigned char)labels[i];
}

// grid = S*B blocks; block = (s, b): flat span [s*SPAN, +SPAN) of row b.
__global__ __launch_bounds__(TPBS) void strat_stream(
    const float* __restrict__ values, const unsigned char* __restrict__ l8,
    unsigned* __restrict__ part, int B, int N, int C, int S, int SPAN, int CPAD) {
    extern __shared__ unsigned acc[];   // [4][CPAD] quadrant-replicated

    const int tid = threadIdx.x;
    const int blk = blockIdx.x;
    const int s   = blk % S;
    const int b   = blk / S;

    for (int i = tid; i < 4 * CPAD; i += TPBS) acc[i] = ENC_NEG_INF;
    __syncthreads();

    const int off0 = s * SPAN;
    const int len  = min(SPAN, N - off0);
    if (len > 0) {
        unsigned* qacc = acc + ((tid & 63) >> 4) * CPAD;  // lane quadrant
        const f4* vp = (const f4*)(values + (size_t)b * N + off0);
        const uchar4* lp = (const uchar4*)(l8 + off0);
        const int nv = len >> 2;

        for (int i = tid; i < nv; i += TPBS) {
            f4 v = vp[i];                                 // 1KB contiguous/instr
            uchar4 L = lp[i];                             // L2/L3-hot
            atomicMax(&qacc[L.x], enc32(__float_as_uint(v.x)));
            atomicMax(&qacc[L.y], enc32(__float_as_uint(v.y)));
            atomicMax(&qacc[L.z], enc32(__float_as_uint(v.z)));
            atomicMax(&qacc[L.w], enc32(__float_as_uint(v.w)));
        }
        for (int i = (nv << 2) + tid; i < len; i += TPBS) {
            atomicMax(&qacc[l8[off0 + i]],
                      enc32(__float_as_uint(values[(size_t)b * N + off0 + i])));
        }
    }
    __syncthreads();

    // flush: max over 4 quadrants -> part[s][b][c]
    unsigned* dst = part + (size_t)s * B * C + (size_t)b * C;
    for (int c = tid; c < C; c += TPBS) {
        unsigned m = max(max(acc[c], acc[CPAD + c]),
                         max(acc[2 * CPAD + c], acc[3 * CPAD + c]));
        dst[c] = m;
    }
}

// out[i] = dec(max over s of part[s*BC + i])
__global__ __launch_bounds__(TPBS) void strat_red(
    const unsigned* __restrict__ part, float* __restrict__ out, int BC, int S) {
    const int i = blockIdx.x * TPBS + threadIdx.x;
    if (i >= BC) return;
    const unsigned* p = part + i;
    unsigned m0 = ENC_NEG_INF, m1 = ENC_NEG_INF, m2 = ENC_NEG_INF, m3 = ENC_NEG_INF;
    int s = 0;
    for (; s + 4 <= S; s += 4) {
        m0 = max(m0, p[(size_t)(s + 0) * BC]);
        m1 = max(m1, p[(size_t)(s + 1) * BC]);
        m2 = max(m2, p[(size_t)(s + 2) * BC]);
        m3 = max(m3, p[(size_t)(s + 3) * BC]);
    }
    for (; s < S; ++s) m0 = max(m0, p[(size_t)s * BC]);
    out[i] = dec32(max(max(m0, m1), max(m2, m3)));
}

// ---------------- fallback (round-1 structure): odd shapes ------------------

#define TPB   256
#define ROWS  8
#define FCPAD 257

__device__ __forceinline__ unsigned encf(float f) {
    return enc32(__float_as_uint(f));
}

__global__ __launch_bounds__(TPB) void strat_init(unsigned* __restrict__ out_enc, int n) {
    int i = blockIdx.x * TPB + threadIdx.x;
    if (i < n) out_enc[i] = ENC_NEG_INF;
}

__global__ __launch_bounds__(TPB) void strat_main_atomic(
    const float* __restrict__ values, const int* __restrict__ labels,
    unsigned* __restrict__ out_enc, int B, int N, int C, int T) {
    __shared__ unsigned acc[ROWS * FCPAD];
    const int tid  = threadIdx.x;
    const int row0 = blockIdx.y * ROWS;
    const int rmax = min(ROWS, B - row0);

    for (int i = tid; i < ROWS * FCPAD; i += TPB) acc[i] = ENC_NEG_INF;
    __syncthreads();

    const int t = blockIdx.x;
#pragma unroll
    for (int e = 0; e < 4; ++e) {
        const int j = t * 1024 + tid * 4 + e;
        if (j < N) {
            const int c = labels[j];
            for (int r = 0; r < rmax; ++r)
                atomicMax(&acc[r * FCPAD + c],
                          encf(values[(size_t)(row0 + r) * N + j]));
        }
    }
    __syncthreads();
    for (int i = tid; i < rmax * C; i += TPB) {
        const int r = i / C, c = i - r * C;
        atomicMax(&out_enc[(size_t)(row0 + r) * C + c], acc[r * FCPAD + c]);
    }
}

__global__ __launch_bounds__(TPB) void strat_decode(unsigned* __restrict__ buf, int n) {
    int i = blockIdx.x * TPB + threadIdx.x;
    if (i < n) {
        float f = dec32(buf[i]);
        ((float*)buf)[i] = f;
    }
}

// ---------------------------------------------------------------------------

extern "C" void kernel_launch(void* const* d_in, const int* in_sizes, int n_in,
                              void* d_out, int out_size, void* d_ws, size_t ws_size,
                              hipStream_t stream) {
    const float* values = (const float*)d_in[0];
    const int*   labels = (const int*)d_in[1];
    const int N  = in_sizes[1];
    const int B  = in_sizes[0] / N;
    const int C  = out_size / B;
    const int BC = B * C;

    const int S    = SMAX;
    const int SPAN = (((N + S - 1) / S) + 3) & ~3;   // 4-aligned span
    const int CPAD = ((C + 31) / 32) * 32 + 1;       // 129 for C=100

    // d_ws layout: [labels8: N bytes][align 256][part: S*BC u32]
    const size_t part_off   = ((size_t)N + 255) & ~(size_t)255;
    const size_t part_bytes = (size_t)S * BC * sizeof(unsigned);
    const size_t lds        = (size_t)4 * CPAD * sizeof(unsigned);

    const bool main_ok = (C <= 128) && (part_off + part_bytes <= ws_size) &&
                         ((size_t)S * SPAN >= (size_t)N);

    if (main_ok) {
        unsigned char* l8   = (unsigned char*)d_ws;
        unsigned*      part = (unsigned*)((char*)d_ws + part_off);

        strat_lab8<<<(N + TPBS - 1) / TPBS, TPBS, 0, stream>>>(labels, l8, N);

        strat_stream<<<S * B, TPBS, lds, stream>>>(
            values, l8, part, B, N, C, S, SPAN, CPAD);

        strat_red<<<(BC + TPBS - 1) / TPBS, TPBS, 0, stream>>>(
            part, (float*)d_out, BC, S);
    } else {
        unsigned* out_enc = (unsigned*)d_out;
        const int init_blocks = (out_size + TPB - 1) / TPB;
        strat_init<<<init_blocks, TPB, 0, stream>>>(out_enc, out_size);
        dim3 grid((N + 1023) / 1024, (B + ROWS - 1) / ROWS);
        strat_main_atomic<<<grid, TPB, 0, stream>>>(values, labels, out_enc, B, N, C,
                                                    (N + 1023) / 1024);
        strat_decode<<<init_blocks, TPB, 0, stream>>>(out_enc, out_size);
    }
}

// Round 9
// 147.557 us; speedup vs baseline: 1.0644x; 1.0644x over previous
//
#include <hip/hip_runtime.h>
#include <hip/hip_bf16.h>

// Stratified max pooling: out[b,c] = max over j with labels[j]==c of values[b,j]
// values: [B, N] fp32, labels: [N] int32, out: [B, C] fp32.
//
// Round 9: round-7 structure (nontemporal contiguous streaming — the config
// that broke the 2.2 TB/s strided-load invariant, total 146.2) with the label
// pre-pack kernel folded away: labels read directly as int4 (L2-hot; blocks
// sharing a span map to the same XCD via blk = b*S + s). 2 dispatches total.
// Quadrant-replicated 2KB LDS acc + fire-and-forget ds_max absorb the scatter.

#define TPBS 256
#define SMAX 16                  // column splits per row
#define ENC_NEG_INF 0x007FFFFFu  // enc(-inf)

typedef float f4 __attribute__((ext_vector_type(4)));

__device__ __forceinline__ unsigned enc32(unsigned u) {
    // monotone float->uint: neg -> ~u, pos -> u|0x80000000  (branchless)
    return u ^ ((unsigned)(((int)u) >> 31) | 0x80000000u);
}
__device__ __forceinline__ float dec32(unsigned u) {
    unsigned b = u ^ (~(unsigned)(((int)u) >> 31) | 0x80000000u);
    return __uint_as_float(b);
}

// grid = B*S blocks; block = (s, b): flat span [s*SPAN, +SPAN) of row b.
// blk = b*S + s  =>  blocks sharing label span s land on the same XCD (s%8).
__global__ __launch_bounds__(TPBS) void strat_stream(
    const float* __restrict__ values, const int* __restrict__ labels,
    unsigned* __restrict__ part, int B, int N, int C, int S, int SPAN, int CPAD) {
    extern __shared__ unsigned acc[];   // [4][CPAD] quadrant-replicated

    const int tid = threadIdx.x;
    const int blk = blockIdx.x;
    const int s   = blk % S;
    const int b   = blk / S;

    for (int i = tid; i < 4 * CPAD; i += TPBS) acc[i] = ENC_NEG_INF;
    __syncthreads();

    const int off0 = s * SPAN;
    const int len  = min(SPAN, N - off0);
    if (len > 0) {
        unsigned* qacc = acc + ((tid & 63) >> 4) * CPAD;  // lane quadrant
        const f4*   vp = (const f4*)(values + (size_t)b * N + off0);
        const int4* lp = (const int4*)(labels + off0);    // L2-hot, XCD-local
        const int nv = len >> 2;

        for (int i = tid; i < nv; i += TPBS) {
            f4 v = __builtin_nontemporal_load(vp + i);    // 1KB contiguous/instr
            int4 L = lp[i];
            atomicMax(&qacc[L.x], enc32(__float_as_uint(v.x)));
            atomicMax(&qacc[L.y], enc32(__float_as_uint(v.y)));
            atomicMax(&qacc[L.z], enc32(__float_as_uint(v.z)));
            atomicMax(&qacc[L.w], enc32(__float_as_uint(v.w)));
        }
        for (int i = (nv << 2) + tid; i < len; i += TPBS) {
            atomicMax(&qacc[labels[off0 + i]],
                      enc32(__float_as_uint(values[(size_t)b * N + off0 + i])));
        }
    }
    __syncthreads();

    // flush: max over 4 quadrants -> part[s][b][c]
    unsigned* dst = part + (size_t)s * B * C + (size_t)b * C;
    for (int c = tid; c < C; c += TPBS) {
        unsigned m = max(max(acc[c], acc[CPAD + c]),
                         max(acc[2 * CPAD + c], acc[3 * CPAD + c]));
        dst[c] = m;
    }
}

// out[i] = dec(max over s of part[s*BC + i])
__global__ __launch_bounds__(TPBS) void strat_red(
    const unsigned* __restrict__ part, float* __restrict__ out, int BC, int S) {
    const int i = blockIdx.x * TPBS + threadIdx.x;
    if (i >= BC) return;
    const unsigned* p = part + i;
    unsigned m0 = ENC_NEG_INF, m1 = ENC_NEG_INF, m2 = ENC_NEG_INF, m3 = ENC_NEG_INF;
    int s = 0;
    for (; s + 4 <= S; s += 4) {
        m0 = max(m0, p[(size_t)(s + 0) * BC]);
        m1 = max(m1, p[(size_t)(s + 1) * BC]);
        m2 = max(m2, p[(size_t)(s + 2) * BC]);
        m3 = max(m3, p[(size_t)(s + 3) * BC]);
    }
    for (; s < S; ++s) m0 = max(m0, p[(size_t)s * BC]);
    out[i] = dec32(max(max(m0, m1), max(m2, m3)));
}

// ---------------- fallback (round-1 structure): odd shapes ------------------

#define TPB   256
#define ROWS  8
#define FCPAD 257

__device__ __forceinline__ unsigned encf(float f) {
    return enc32(__float_as_uint(f));
}

__global__ __launch_bounds__(TPB) void strat_init(unsigned* __restrict__ out_enc, int n) {
    int i = blockIdx.x * TPB + threadIdx.x;
    if (i < n) out_enc[i] = ENC_NEG_INF;
}

__global__ __launch_bounds__(TPB) void strat_main_atomic(
    const float* __restrict__ values, const int* __restrict__ labels,
    unsigned* __restrict__ out_enc, int B, int N, int C, int T) {
    __shared__ unsigned acc[ROWS * FCPAD];
    const int tid  = threadIdx.x;
    const int row0 = blockIdx.y * ROWS;
    const int rmax = min(ROWS, B - row0);

    for (int i = tid; i < ROWS * FCPAD; i += TPB) acc[i] = ENC_NEG_INF;
    __syncthreads();

    const int t = blockIdx.x;
#pragma unroll
    for (int e = 0; e < 4; ++e) {
        const int j = t * 1024 + tid * 4 + e;
        if (j < N) {
            const int c = labels[j];
            for (int r = 0; r < rmax; ++r)
                atomicMax(&acc[r * FCPAD + c],
                          encf(values[(size_t)(row0 + r) * N + j]));
        }
    }
    __syncthreads();
    for (int i = tid; i < rmax * C; i += TPB) {
        const int r = i / C, c = i - r * C;
        atomicMax(&out_enc[(size_t)(row0 + r) * C + c], acc[r * FCPAD + c]);
    }
}

__global__ __launch_bounds__(TPB) void strat_decode(unsigned* __restrict__ buf, int n) {
    int i = blockIdx.x * TPB + threadIdx.x;
    if (i < n) {
        float f = dec32(buf[i]);
        ((float*)buf)[i] = f;
    }
}

// ---------------------------------------------------------------------------

extern "C" void kernel_launch(void* const* d_in, const int* in_sizes, int n_in,
                              void* d_out, int out_size, void* d_ws, size_t ws_size,
                              hipStream_t stream) {
    const float* values = (const float*)d_in[0];
    const int*   labels = (const int*)d_in[1];
    const int N  = in_sizes[1];
    const int B  = in_sizes[0] / N;
    const int C  = out_size / B;
    const int BC = B * C;

    const int S    = SMAX;
    const int SPAN = (((N + S - 1) / S) + 3) & ~3;   // 4-aligned span
    const int CPAD = ((C + 31) / 32) * 32 + 1;       // 129 for C=100

    const size_t part_bytes = (size_t)S * BC * sizeof(unsigned);
    const size_t lds        = (size_t)4 * CPAD * sizeof(unsigned);

    const bool main_ok = (C <= 1024) && (part_bytes <= ws_size) &&
                         (lds <= 64 * 1024) &&
                         ((size_t)S * SPAN >= (size_t)N);

    if (main_ok) {
        unsigned* part = (unsigned*)d_ws;

        strat_stream<<<B * S, TPBS, lds, stream>>>(
            values, labels, part, B, N, C, S, SPAN, CPAD);

        strat_red<<<(BC + TPBS - 1) / TPBS, TPBS, 0, stream>>>(
            part, (float*)d_out, BC, S);
    } else {
        unsigned* out_enc = (unsigned*)d_out;
        const int init_blocks = (out_size + TPB - 1) / TPB;
        strat_init<<<init_blocks, TPB, 0, stream>>>(out_enc, out_size);
        dim3 grid((N + 1023) / 1024, (B + ROWS - 1) / ROWS);
        strat_main_atomic<<<grid, TPB, 0, stream>>>(values, labels, out_enc, B, N, C,
                                                    (N + 1023) / 1024);
        strat_decode<<<init_blocks, TPB, 0, stream>>>(out_enc, out_size);
    }
}